// Round 6
// baseline (398.635 us; speedup 1.0000x reference)
//
#include <hip/hip_runtime.h>
#include <hip/hip_bf16.h>
#include <stdint.h>

// Attention_5265629905090: B=4, S=4096, D=256, fp32 in/out, int mask (1 = masked -> -1e9)
// R6: mask bit-pack prepass. R5 showed attn running AT its achieved HBM rate (1.08 TB/s)
// with 64B-granule mask reads = pattern-bound. Pack 268MB int32 -> 8MB bits in a coalesced
// streaming kernel (ballot), attn reads broadcast u64 words. Occupancy-via-grid (R5) was a
// bust: 240 VGPR + accums ~= 368/wave -> 1 wave/SIMD regardless; attack traffic instead.

typedef __attribute__((ext_vector_type(8))) short bf16x8;
typedef __attribute__((ext_vector_type(4))) float f32x4;

__device__ __forceinline__ short f2bf(float f) {
    union { float f; uint32_t u; } v; v.f = f;
    uint32_t r = v.u + 0x7FFFu + ((v.u >> 16) & 1u);   // RNE
    return (short)(r >> 16);
}
__device__ __forceinline__ float bf2f(short s) {
    union { uint32_t u; float f; } v; v.u = ((uint32_t)(uint16_t)s) << 16;
    return v.f;
}

// ---------------------------------------------------------------------------
// Projection GEMM: C[s][e] = sum_d X[s][d] * W[e][d]   (nn.Linear, y = x W^T)
// grid (128, 3), block 256.  proj: 0=Q (scaled 1/16), 1=K, 2=V^T
// ---------------------------------------------------------------------------
__global__ __launch_bounds__(256, 1)
void proj_kernel(const float* __restrict__ encq,
                 const float* __restrict__ enck,
                 const float* __restrict__ encv,
                 const float* __restrict__ Wq,
                 const float* __restrict__ Wk,
                 const float* __restrict__ Wv,
                 short* __restrict__ q_out,   // [16384][256]
                 short* __restrict__ k_out,   // [16384][256]
                 short* __restrict__ vt_out)  // [4][256][4096]
{
    __shared__ short As[128][72];   // 72-short rows: 144B = 16B-aligned, bank-spread
    __shared__ short Bs[256][72];

    const int tid = threadIdx.x;
    const int wave = tid >> 6, lane = tid & 63, lo = lane & 15, hi = lane >> 4;
    const int proj = blockIdx.y;
    const int row0 = blockIdx.x * 128;

    const float* X = (proj == 0) ? encq : (proj == 1) ? enck : encv;
    const float* W = (proj == 0) ? Wq   : (proj == 1) ? Wk   : Wv;

    f32x4 acc[2][16];
    #pragma unroll
    for (int m = 0; m < 2; ++m)
        #pragma unroll
        for (int n = 0; n < 16; ++n) {
            f32x4 z = {0.f, 0.f, 0.f, 0.f};
            acc[m][n] = z;
        }

    for (int ks = 0; ks < 4; ++ks) {
        const int k0 = ks * 64;
        __syncthreads();
        // stage A tile: 128 rows x 64 cols fp32 -> bf16
        #pragma unroll
        for (int i = 0; i < 8; ++i) {
            int u = tid + i * 256;
            int r = u >> 4, c4 = u & 15;
            float4 v = *(const float4*)(X + (size_t)(row0 + r) * 256 + k0 + c4 * 4);
            short* dst = &As[r][c4 * 4];
            dst[0] = f2bf(v.x); dst[1] = f2bf(v.y); dst[2] = f2bf(v.z); dst[3] = f2bf(v.w);
        }
        // stage W tile: 256 rows x 64 cols
        #pragma unroll
        for (int i = 0; i < 16; ++i) {
            int u = tid + i * 256;
            int r = u >> 4, c4 = u & 15;
            float4 v = *(const float4*)(W + (size_t)r * 256 + k0 + c4 * 4);
            short* dst = &Bs[r][c4 * 4];
            dst[0] = f2bf(v.x); dst[1] = f2bf(v.y); dst[2] = f2bf(v.z); dst[3] = f2bf(v.w);
        }
        __syncthreads();
        #pragma unroll
        for (int kl = 0; kl < 2; ++kl) {
            bf16x8 a[2];
            #pragma unroll
            for (int m = 0; m < 2; ++m)
                a[m] = *(const bf16x8*)&As[wave * 32 + m * 16 + lo][kl * 32 + hi * 8];
            #pragma unroll
            for (int n = 0; n < 16; ++n) {
                bf16x8 b = *(const bf16x8*)&Bs[n * 16 + lo][kl * 32 + hi * 8];
                #pragma unroll
                for (int m = 0; m < 2; ++m)
                    acc[m][n] = __builtin_amdgcn_mfma_f32_16x16x32_bf16(a[m], b, acc[m][n], 0, 0, 0);
            }
        }
    }

    // epilogue: C-frag row = (lane>>4)*4 + j, col = lane&15  (m89/m91-verified)
    #pragma unroll
    for (int m = 0; m < 2; ++m)
        #pragma unroll
        for (int n = 0; n < 16; ++n)
            #pragma unroll
            for (int j = 0; j < 4; ++j) {
                int srow = row0 + wave * 32 + m * 16 + hi * 4 + j;
                int e = n * 16 + lo;
                float v = acc[m][n][j];
                if (proj == 0) {
                    q_out[(size_t)srow * 256 + e] = f2bf(v * 0.0625f);  // fold 1/sqrt(256)
                } else if (proj == 1) {
                    k_out[(size_t)srow * 256 + e] = f2bf(v);
                } else {
                    int b = srow >> 12, s = srow & 4095;
                    vt_out[((size_t)b * 256 + e) * 4096 + s] = f2bf(v);
                }
            }
}

// ---------------------------------------------------------------------------
// Mask bit-pack: [16384][4096] int32 -> [16384][64] u64 (bit k = mask!=0).
// One wave packs 4 full rows; per 64-lane iter: coalesced 256B load + ballot.
// grid 1024, block 256 (4096 waves x 4 rows).
// ---------------------------------------------------------------------------
__global__ __launch_bounds__(256)
void maskpack_kernel(const int* __restrict__ mask,
                     unsigned long long* __restrict__ packed)
{
    const int wv = (blockIdx.x * 256 + threadIdx.x) >> 6;   // 0..4095
    const int lane = threadIdx.x & 63;
    for (int rr = 0; rr < 4; ++rr) {
        const size_t row = (size_t)wv * 4 + rr;
        const int* src = mask + row * 4096;
        unsigned long long myword = 0;
        #pragma unroll
        for (int it = 0; it < 64; ++it) {
            int v = src[it * 64 + lane];                     // 256B coalesced
            unsigned long long w = __ballot(v != 0);
            if (lane == it) myword = w;
        }
        packed[row * 64 + lane] = myword;                    // 512B coalesced
    }
}

// ---------------------------------------------------------------------------
// Flash attention, split-KV x4. grid (32, 4, 4), block 256 (4 waves x 32 q-rows).
// KVBLK = 64, 16 tiles/block. PACKED: mask as broadcast u64 bit-words.
// ---------------------------------------------------------------------------
template<bool PACKED>
__global__ __launch_bounds__(256, 1)
void attn_kernel(const short* __restrict__ qs,   // [16384][256] prescaled
                 const short* __restrict__ kk_,  // [16384][256]
                 const short* __restrict__ vt,   // [4][256][4096]
                 const int*   __restrict__ mask, // [4][4096][4096]
                 const unsigned long long* __restrict__ pk, // [16384][64] or null
                 short* __restrict__ Opart,      // [4][16384][256] bf16
                 float* __restrict__ Mpart,      // [4][16384]
                 float* __restrict__ Lpart)      // [4][16384]
{
    __shared__ short Ks[64][264];      // 33792 B
    __shared__ short Vs[256][72];      // 36864 B
    __shared__ short Ps[4][32][40];    // 10240 B   (total 80896)

    const int tid = threadIdx.x;
    const int wave = tid >> 6, lane = tid & 63, lo = lane & 15, hi = lane >> 4;
    const int qt = blockIdx.x, b = blockIdx.y, split = blockIdx.z;
    const int qrow0 = qt * 128 + wave * 32;           // q row base within batch
    const size_t qg0 = (size_t)b * 4096 + qrow0;      // global q row base
    const int kv0 = split * 1024;

    // resident Q fragments: A-frag row = lane&15, k = (lane>>4)*8..+8
    bf16x8 qf[2][8];
    #pragma unroll
    for (int m = 0; m < 2; ++m)
        #pragma unroll
        for (int kk = 0; kk < 8; ++kk)
            qf[m][kk] = *(const bf16x8*)(qs + (qg0 + m * 16 + lo) * 256 + kk * 32 + hi * 8);

    f32x4 oacc[2][16];
    #pragma unroll
    for (int m = 0; m < 2; ++m)
        #pragma unroll
        for (int n = 0; n < 16; ++n) {
            f32x4 z = {0.f, 0.f, 0.f, 0.f};
            oacc[m][n] = z;
        }
    float Mst[2][4], Lst[2][4];
    #pragma unroll
    for (int m = 0; m < 2; ++m)
        #pragma unroll
        for (int j = 0; j < 4; ++j) { Mst[m][j] = -1e30f; Lst[m][j] = 0.f; }

    bf16x8 onesf;
    #pragma unroll
    for (int i = 0; i < 8; ++i) onesf[i] = (short)0x3F80;   // bf16 1.0

    const short* ksrc0 = kk_ + ((size_t)b * 4096 + kv0) * 256;
    const size_t vbase = (size_t)b * 256 * 4096;
    const int* mbase = mask + (size_t)b * 4096 * 4096;
    const unsigned long long* pkbase = pk + qg0 * 64 + split * 16;

    for (int t = 0; t < 16; ++t) {
        __syncthreads();   // prior iteration done reading Ks/Vs
        // --- stage K tile (64x256, contiguous 32KB) ---
        {
            const short* src = ksrc0 + (size_t)t * 64 * 256;
            #pragma unroll
            for (int i = 0; i < 8; ++i) {
                int u = tid + i * 256;
                bf16x8 v = *(const bf16x8*)(src + u * 8);
                *(bf16x8*)&Ks[u >> 5][(u & 31) * 8] = v;
            }
        }
        // --- stage V^T tile (256 x 64): 2048 bf16x8 units ---
        {
            const int c0 = kv0 + t * 64;
            #pragma unroll
            for (int i = 0; i < 8; ++i) {
                int u = tid + i * 256;
                int r = u >> 3, cu = u & 7;
                bf16x8 v = *(const bf16x8*)(vt + vbase + (size_t)r * 4096 + c0 + cu * 8);
                *(bf16x8*)&Vs[r][cu * 8] = v;
            }
        }
        __syncthreads();

        // --- mask: per-thread bit-words (PACKED) or int loads (legacy) ---
        unsigned long long wls[2][4];   // word >> lo  (bit n*16 tests col n*16+lo)
        int mrg[2][4][4];
        if constexpr (PACKED) {
            #pragma unroll
            for (int m = 0; m < 2; ++m)
                #pragma unroll
                for (int j = 0; j < 4; ++j)
                    wls[m][j] = pkbase[(size_t)(m * 16 + hi * 4 + j) * 64 + t] >> lo;
        } else {
            #pragma unroll
            for (int m = 0; m < 2; ++m)
                #pragma unroll
                for (int n = 0; n < 4; ++n)
                    #pragma unroll
                    for (int j = 0; j < 4; ++j)
                        mrg[m][n][j] = mbase[(size_t)(qrow0 + m * 16 + hi * 4 + j) * 4096
                                             + kv0 + t * 64 + n * 16 + lo];
        }

        // --- QK^T: S[32q][64k] ---
        f32x4 sacc[2][4];
        #pragma unroll
        for (int m = 0; m < 2; ++m)
            #pragma unroll
            for (int n = 0; n < 4; ++n) {
                f32x4 z = {0.f, 0.f, 0.f, 0.f};
                sacc[m][n] = z;
            }
        #pragma unroll
        for (int kk = 0; kk < 8; ++kk) {
            #pragma unroll
            for (int n = 0; n < 4; ++n) {
                bf16x8 bk = *(const bf16x8*)&Ks[n * 16 + lo][kk * 32 + hi * 8];
                #pragma unroll
                for (int m = 0; m < 2; ++m)
                    sacc[m][n] = __builtin_amdgcn_mfma_f32_16x16x32_bf16(qf[m][kk], bk, sacc[m][n], 0, 0, 0);
            }
        }

        // --- row max (masked), butterfly over the 16-lane column group ---
        float ml[2][4];
        #pragma unroll
        for (int m = 0; m < 2; ++m)
            #pragma unroll
            for (int j = 0; j < 4; ++j) {
                float mx = -1e30f;
                #pragma unroll
                for (int n = 0; n < 4; ++n) {
                    float s = sacc[m][n][j];
                    bool msk;
                    if constexpr (PACKED) msk = (wls[m][j] >> (n * 16)) & 1ull;
                    else                  msk = mrg[m][n][j] != 0;
                    if (msk) s = -1e30f;
                    mx = fmaxf(mx, s);
                }
                #pragma unroll
                for (int d = 1; d < 16; d <<= 1)
                    mx = fmaxf(mx, __shfl_xor(mx, d));
                ml[m][j] = mx;
            }

        // --- defer-max rescale (THR = 8) ---
        bool needl = false;
        #pragma unroll
        for (int m = 0; m < 2; ++m)
            #pragma unroll
            for (int j = 0; j < 4; ++j)
                needl = needl || (ml[m][j] > Mst[m][j] + 8.0f);
        if (__any((int)needl)) {
            #pragma unroll
            for (int m = 0; m < 2; ++m)
                #pragma unroll
                for (int j = 0; j < 4; ++j) {
                    float Mn = fmaxf(Mst[m][j], ml[m][j]);
                    float sc = __expf(Mst[m][j] - Mn);
                    Mst[m][j] = Mn;
                    Lst[m][j] *= sc;
                    #pragma unroll
                    for (int n = 0; n < 16; ++n) oacc[m][n][j] *= sc;
                }
        }

        // --- PV in two k-halves through the half-size P buffer ---
        f32x4 lacc[2];
        {
            f32x4 z = {0.f, 0.f, 0.f, 0.f};
            lacc[0] = z; lacc[1] = z;
        }
        #pragma unroll
        for (int g = 0; g < 2; ++g) {
            // write P-half (exp, mask->0) transposed into per-wave buffer
            #pragma unroll
            for (int m = 0; m < 2; ++m)
                #pragma unroll
                for (int nn = 0; nn < 2; ++nn) {
                    int n = g * 2 + nn;
                    #pragma unroll
                    for (int j = 0; j < 4; ++j) {
                        float p = __expf(sacc[m][n][j] - Mst[m][j]);
                        bool msk;
                        if constexpr (PACKED) msk = (wls[m][j] >> (n * 16)) & 1ull;
                        else                  msk = mrg[m][n][j] != 0;
                        if (msk) p = 0.0f;
                        Ps[wave][m * 16 + hi * 4 + j][nn * 16 + lo] = f2bf(p);
                    }
                }
            // read A-frags (same wave; compiler orders lgkm)
            bf16x8 a2[2];
            #pragma unroll
            for (int m = 0; m < 2; ++m)
                a2[m] = *(const bf16x8*)&Ps[wave][m * 16 + lo][hi * 8];
            #pragma unroll
            for (int n = 0; n < 16; ++n) {
                bf16x8 bv = *(const bf16x8*)&Vs[n * 16 + lo][g * 32 + hi * 8];
                #pragma unroll
                for (int m = 0; m < 2; ++m)
                    oacc[m][n] = __builtin_amdgcn_mfma_f32_16x16x32_bf16(a2[m], bv, oacc[m][n], 0, 0, 0);
            }
            #pragma unroll
            for (int m = 0; m < 2; ++m)
                lacc[m] = __builtin_amdgcn_mfma_f32_16x16x32_bf16(a2[m], onesf, lacc[m], 0, 0, 0);
        }
        #pragma unroll
        for (int m = 0; m < 2; ++m)
            #pragma unroll
            for (int j = 0; j < 4; ++j)
                Lst[m][j] += lacc[m][j];
    }

    // --- epilogue: bf16 raw partials ---
    const size_t obase = ((size_t)split * 16384 + qg0) * 256;
    #pragma unroll
    for (int m = 0; m < 2; ++m)
        #pragma unroll
        for (int n = 0; n < 16; ++n)
            #pragma unroll
            for (int j = 0; j < 4; ++j)
                Opart[obase + (size_t)(m * 16 + hi * 4 + j) * 256 + n * 16 + lo] =
                    f2bf(oacc[m][n][j]);
    if (lo == 0) {
        #pragma unroll
        for (int m = 0; m < 2; ++m)
            #pragma unroll
            for (int j = 0; j < 4; ++j) {
                size_t r = (size_t)split * 16384 + qg0 + m * 16 + hi * 4 + j;
                Mpart[r] = Mst[m][j];
                Lpart[r] = Lst[m][j];
            }
    }
}

// ---------------------------------------------------------------------------
// Combine the four KV-split partials.  grid 4096, block 256, 4 floats/thread.
// ---------------------------------------------------------------------------
__global__ __launch_bounds__(256)
void combine_kernel(const short* __restrict__ Opart,
                    const float* __restrict__ Mpart,
                    const float* __restrict__ Lpart,
                    float* __restrict__ out)
{
    int gid = blockIdx.x * 256 + threadIdx.x;   // 1,048,576 threads
    int row = gid >> 6, c4 = gid & 63;
    float Ms[4], Ls[4], M = -1e30f;
    #pragma unroll
    for (int sp = 0; sp < 4; ++sp) {
        Ms[sp] = Mpart[sp * 16384 + row];
        Ls[sp] = Lpart[sp * 16384 + row];
        M = fmaxf(M, Ms[sp]);
    }
    float w[4], denom = 0.f;
    #pragma unroll
    for (int sp = 0; sp < 4; ++sp) {
        w[sp] = __expf(Ms[sp] - M);
        denom += w[sp] * Ls[sp];
    }
    float inv = 1.0f / denom;
    float4 r = {0.f, 0.f, 0.f, 0.f};
    #pragma unroll
    for (int sp = 0; sp < 4; ++sp) {
        short4 o = *(const short4*)(Opart + ((size_t)sp * 16384 + row) * 256 + c4 * 4);
        r.x += w[sp] * bf2f(o.x);
        r.y += w[sp] * bf2f(o.y);
        r.z += w[sp] * bf2f(o.z);
        r.w += w[sp] * bf2f(o.w);
    }
    r.x *= inv; r.y *= inv; r.z *= inv; r.w *= inv;
    *(float4*)(out + (size_t)row * 256 + c4 * 4) = r;
}

// ---------------------------------------------------------------------------
extern "C" void kernel_launch(void* const* d_in, const int* in_sizes, int n_in,
                              void* d_out, int out_size, void* d_ws, size_t ws_size,
                              hipStream_t stream)
{
    const float* encq = (const float*)d_in[0];
    const float* enck = (const float*)d_in[1];
    const float* encv = (const float*)d_in[2];
    const int*   mask = (const int*)d_in[3];
    const float* Wq   = (const float*)d_in[4];
    const float* Wk   = (const float*)d_in[5];
    const float* Wv   = (const float*)d_in[6];

    char* ws = (char*)d_ws;
    short* q_ws  = (short*)(ws);                  //  8 MB  [16384][256] bf16
    short* k_ws  = (short*)(ws + 8388608);        //  8 MB
    short* vt_ws = (short*)(ws + 16777216);       //  8 MB  [4][256][4096] bf16
    short* Opart = (short*)(ws + 25165824);       // 32 MB  [4][16384][256] bf16
    float* Mpart = (float*)(ws + 58720256);       // 256 KB [4][16384]
    float* Lpart = (float*)(ws + 58982400);       // 256 KB
    unsigned long long* packed = (unsigned long long*)(ws + 59244544);  // 8 MB
    const size_t WS_NEEDED_PACKED = 59244544u + 8388608u;               // ~67.6 MB
    float* out   = (float*)d_out;

    hipLaunchKernelGGL(proj_kernel, dim3(128, 3), dim3(256), 0, stream,
                       encq, enck, encv, Wq, Wk, Wv, q_ws, k_ws, vt_ws);
    if (ws_size >= WS_NEEDED_PACKED) {
        hipLaunchKernelGGL(maskpack_kernel, dim3(1024), dim3(256), 0, stream,
                           mask, packed);
        hipLaunchKernelGGL((attn_kernel<true>), dim3(32, 4, 4), dim3(256), 0, stream,
                           q_ws, k_ws, vt_ws, mask, packed, Opart, Mpart, Lpart);
    } else {
        hipLaunchKernelGGL((attn_kernel<false>), dim3(32, 4, 4), dim3(256), 0, stream,
                           q_ws, k_ws, vt_ws, mask, packed, Opart, Mpart, Lpart);
    }
    hipLaunchKernelGGL(combine_kernel, dim3(4096), dim3(256), 0, stream,
                       Opart, Mpart, Lpart, out);
}

// Round 7
// 324.937 us; speedup vs baseline: 1.2268x; 1.2268x over previous
//
#include <hip/hip_runtime.h>
#include <hip/hip_bf16.h>
#include <stdint.h>

// Attention_5265629905090: B=4, S=4096, D=256, fp32 in/out, int mask (1 = masked -> -1e9)
// R7: (a) maskpack rewritten ballot-free (thread-local 256B read + bit pack) — R6's ballot
// version ran at 2 TB/s / ~134us. (b) attn restructured 8 waves x 16 q-rows (QBLK=128,
// oacc 64 regs/wave, launch_bounds(512,2) -> target 2 waves/SIMD; R5/R6 showed 368-reg
// waves pin occupancy at 1/SIMD and 60% of attn time is latency stall). Split-KV x2.

typedef __attribute__((ext_vector_type(8))) short bf16x8;
typedef __attribute__((ext_vector_type(4))) float f32x4;

__device__ __forceinline__ short f2bf(float f) {
    union { float f; uint32_t u; } v; v.f = f;
    uint32_t r = v.u + 0x7FFFu + ((v.u >> 16) & 1u);   // RNE
    return (short)(r >> 16);
}
__device__ __forceinline__ float bf2f(short s) {
    union { uint32_t u; float f; } v; v.u = ((uint32_t)(uint16_t)s) << 16;
    return v.f;
}

// ---------------------------------------------------------------------------
// Projection GEMM: C[s][e] = sum_d X[s][d] * W[e][d]   (nn.Linear, y = x W^T)
// grid (128, 3), block 256.  proj: 0=Q (scaled 1/16), 1=K, 2=V^T
// ---------------------------------------------------------------------------
__global__ __launch_bounds__(256, 1)
void proj_kernel(const float* __restrict__ encq,
                 const float* __restrict__ enck,
                 const float* __restrict__ encv,
                 const float* __restrict__ Wq,
                 const float* __restrict__ Wk,
                 const float* __restrict__ Wv,
                 short* __restrict__ q_out,   // [16384][256]
                 short* __restrict__ k_out,   // [16384][256]
                 short* __restrict__ vt_out)  // [4][256][4096]
{
    __shared__ short As[128][72];
    __shared__ short Bs[256][72];

    const int tid = threadIdx.x;
    const int wave = tid >> 6, lane = tid & 63, lo = lane & 15, hi = lane >> 4;
    const int proj = blockIdx.y;
    const int row0 = blockIdx.x * 128;

    const float* X = (proj == 0) ? encq : (proj == 1) ? enck : encv;
    const float* W = (proj == 0) ? Wq   : (proj == 1) ? Wk   : Wv;

    f32x4 acc[2][16];
    #pragma unroll
    for (int m = 0; m < 2; ++m)
        #pragma unroll
        for (int n = 0; n < 16; ++n) {
            f32x4 z = {0.f, 0.f, 0.f, 0.f};
            acc[m][n] = z;
        }

    for (int ks = 0; ks < 4; ++ks) {
        const int k0 = ks * 64;
        __syncthreads();
        #pragma unroll
        for (int i = 0; i < 8; ++i) {
            int u = tid + i * 256;
            int r = u >> 4, c4 = u & 15;
            float4 v = *(const float4*)(X + (size_t)(row0 + r) * 256 + k0 + c4 * 4);
            short* dst = &As[r][c4 * 4];
            dst[0] = f2bf(v.x); dst[1] = f2bf(v.y); dst[2] = f2bf(v.z); dst[3] = f2bf(v.w);
        }
        #pragma unroll
        for (int i = 0; i < 16; ++i) {
            int u = tid + i * 256;
            int r = u >> 4, c4 = u & 15;
            float4 v = *(const float4*)(W + (size_t)r * 256 + k0 + c4 * 4);
            short* dst = &Bs[r][c4 * 4];
            dst[0] = f2bf(v.x); dst[1] = f2bf(v.y); dst[2] = f2bf(v.z); dst[3] = f2bf(v.w);
        }
        __syncthreads();
        #pragma unroll
        for (int kl = 0; kl < 2; ++kl) {
            bf16x8 a[2];
            #pragma unroll
            for (int m = 0; m < 2; ++m)
                a[m] = *(const bf16x8*)&As[wave * 32 + m * 16 + lo][kl * 32 + hi * 8];
            #pragma unroll
            for (int n = 0; n < 16; ++n) {
                bf16x8 b = *(const bf16x8*)&Bs[n * 16 + lo][kl * 32 + hi * 8];
                #pragma unroll
                for (int m = 0; m < 2; ++m)
                    acc[m][n] = __builtin_amdgcn_mfma_f32_16x16x32_bf16(a[m], b, acc[m][n], 0, 0, 0);
            }
        }
    }

    #pragma unroll
    for (int m = 0; m < 2; ++m)
        #pragma unroll
        for (int n = 0; n < 16; ++n)
            #pragma unroll
            for (int j = 0; j < 4; ++j) {
                int srow = row0 + wave * 32 + m * 16 + hi * 4 + j;
                int e = n * 16 + lo;
                float v = acc[m][n][j];
                if (proj == 0) {
                    q_out[(size_t)srow * 256 + e] = f2bf(v * 0.0625f);
                } else if (proj == 1) {
                    k_out[(size_t)srow * 256 + e] = f2bf(v);
                } else {
                    int b = srow >> 12, s = srow & 4095;
                    vt_out[((size_t)b * 256 + e) * 4096 + s] = f2bf(v);
                }
            }
}

// ---------------------------------------------------------------------------
// Mask bit-pack v2 (ballot-free): one thread -> one u64 word. Each thread reads
// its own 64 consecutive ints (16 x int4, 256B contiguous) and packs locally.
// grid 4096, block 256.  [16384][4096] int32 -> [16384][64] u64.
// ---------------------------------------------------------------------------
__global__ __launch_bounds__(256)
void maskpack_kernel(const int* __restrict__ mask,
                     unsigned long long* __restrict__ packed)
{
    const int gid = blockIdx.x * 256 + threadIdx.x;   // 0 .. 1048575
    const int row = gid >> 6, w = gid & 63;
    const int4* src = (const int4*)(mask + (size_t)row * 4096 + w * 64);
    uint32_t lo32 = 0, hi32 = 0;
    #pragma unroll
    for (int it = 0; it < 8; ++it) {
        int4 v = src[it];
        lo32 |= (uint32_t)(v.x != 0) << (it * 4);
        lo32 |= (uint32_t)(v.y != 0) << (it * 4 + 1);
        lo32 |= (uint32_t)(v.z != 0) << (it * 4 + 2);
        lo32 |= (uint32_t)(v.w != 0) << (it * 4 + 3);
    }
    #pragma unroll
    for (int it = 0; it < 8; ++it) {
        int4 v = src[8 + it];
        hi32 |= (uint32_t)(v.x != 0) << (it * 4);
        hi32 |= (uint32_t)(v.y != 0) << (it * 4 + 1);
        hi32 |= (uint32_t)(v.z != 0) << (it * 4 + 2);
        hi32 |= (uint32_t)(v.w != 0) << (it * 4 + 3);
    }
    packed[(size_t)row * 64 + w] = (unsigned long long)lo32
                                 | ((unsigned long long)hi32 << 32);
}

// ---------------------------------------------------------------------------
// Flash attention, split-KV x2. grid (32, 4, 2), block 512 (8 waves x 16 q-rows,
// QBLK=128). KVBLK = 64, 32 tiles/block. LDS 80896 B. oacc 64 regs/wave ->
// launch_bounds(512,2) targets 2 waves/SIMD.
// ---------------------------------------------------------------------------
__global__ __launch_bounds__(512, 2)
void attn_kernel(const short* __restrict__ qs,   // [16384][256] prescaled
                 const short* __restrict__ kk_,  // [16384][256]
                 const short* __restrict__ vt,   // [4][256][4096]
                 const unsigned long long* __restrict__ pk, // [16384][64]
                 short* __restrict__ Opart,      // [2][16384][256] bf16
                 float* __restrict__ Mpart,      // [2][16384]
                 float* __restrict__ Lpart)      // [2][16384]
{
    __shared__ short Ks[64][264];      // 33792 B
    __shared__ short Vs[256][72];      // 36864 B
    __shared__ short Ps[8][16][40];    // 10240 B   (total 80896)

    const int tid = threadIdx.x;
    const int wave = tid >> 6, lane = tid & 63, lo = lane & 15, hi = lane >> 4;
    const int qt = blockIdx.x, b = blockIdx.y, split = blockIdx.z;
    const int qrow0 = qt * 128 + wave * 16;           // q row base within batch
    const size_t qg0 = (size_t)b * 4096 + qrow0;      // global q row base
    const int kv0 = split * 2048;

    // resident Q fragments (16 rows): A-frag row = lane&15, k = (lane>>4)*8..+8
    bf16x8 qf[8];
    #pragma unroll
    for (int kk = 0; kk < 8; ++kk)
        qf[kk] = *(const bf16x8*)(qs + (qg0 + lo) * 256 + kk * 32 + hi * 8);

    f32x4 oacc[16];
    #pragma unroll
    for (int n = 0; n < 16; ++n) {
        f32x4 z = {0.f, 0.f, 0.f, 0.f};
        oacc[n] = z;
    }
    float Mst[4], Lst[4];
    #pragma unroll
    for (int j = 0; j < 4; ++j) { Mst[j] = -1e30f; Lst[j] = 0.f; }

    bf16x8 onesf;
    #pragma unroll
    for (int i = 0; i < 8; ++i) onesf[i] = (short)0x3F80;   // bf16 1.0

    const short* ksrc0 = kk_ + ((size_t)b * 4096 + kv0) * 256;
    const size_t vbase = (size_t)b * 256 * 4096;
    const unsigned long long* pkbase = pk + qg0 * 64 + split * 32;

    for (int t = 0; t < 32; ++t) {
        __syncthreads();   // prior iteration done reading Ks/Vs
        // --- stage K tile (64x256): 2048 bf16x8 units over 512 threads ---
        {
            const short* src = ksrc0 + (size_t)t * 64 * 256;
            #pragma unroll
            for (int i = 0; i < 4; ++i) {
                int u = tid + i * 512;
                bf16x8 v = *(const bf16x8*)(src + u * 8);
                *(bf16x8*)&Ks[u >> 5][(u & 31) * 8] = v;
            }
        }
        // --- stage V^T tile (256 x 64): 2048 bf16x8 units ---
        {
            const int c0 = kv0 + t * 64;
            #pragma unroll
            for (int i = 0; i < 4; ++i) {
                int u = tid + i * 512;
                int r = u >> 3, cu = u & 7;
                bf16x8 v = *(const bf16x8*)(vt + vbase + (size_t)r * 4096 + c0 + cu * 8);
                *(bf16x8*)&Vs[r][cu * 8] = v;
            }
        }
        __syncthreads();

        // --- mask bit-words: row hi*4+j, bit (n*16+lo) after >>lo ---
        unsigned long long wls[4];
        #pragma unroll
        for (int j = 0; j < 4; ++j)
            wls[j] = pkbase[(size_t)(hi * 4 + j) * 64 + t] >> lo;

        // --- QK^T: S[16q][64k] ---
        f32x4 sacc[4];
        #pragma unroll
        for (int n = 0; n < 4; ++n) {
            f32x4 z = {0.f, 0.f, 0.f, 0.f};
            sacc[n] = z;
        }
        #pragma unroll
        for (int kk = 0; kk < 8; ++kk) {
            #pragma unroll
            for (int n = 0; n < 4; ++n) {
                bf16x8 bk = *(const bf16x8*)&Ks[n * 16 + lo][kk * 32 + hi * 8];
                sacc[n] = __builtin_amdgcn_mfma_f32_16x16x32_bf16(qf[kk], bk, sacc[n], 0, 0, 0);
            }
        }

        // --- row max (masked), butterfly over the 16-lane column group ---
        float ml[4];
        #pragma unroll
        for (int j = 0; j < 4; ++j) {
            float mx = -1e30f;
            #pragma unroll
            for (int n = 0; n < 4; ++n) {
                float s = sacc[n][j];
                if ((wls[j] >> (n * 16)) & 1ull) s = -1e30f;
                mx = fmaxf(mx, s);
            }
            #pragma unroll
            for (int d = 1; d < 16; d <<= 1)
                mx = fmaxf(mx, __shfl_xor(mx, d));
            ml[j] = mx;
        }

        // --- defer-max rescale (THR = 8) ---
        bool needl = false;
        #pragma unroll
        for (int j = 0; j < 4; ++j)
            needl = needl || (ml[j] > Mst[j] + 8.0f);
        if (__any((int)needl)) {
            #pragma unroll
            for (int j = 0; j < 4; ++j) {
                float Mn = fmaxf(Mst[j], ml[j]);
                float sc = __expf(Mst[j] - Mn);
                Mst[j] = Mn;
                Lst[j] *= sc;
                #pragma unroll
                for (int n = 0; n < 16; ++n) oacc[n][j] *= sc;
            }
        }

        // --- PV in two k-halves through the per-wave P buffer ---
        f32x4 lacc = {0.f, 0.f, 0.f, 0.f};
        #pragma unroll
        for (int g = 0; g < 2; ++g) {
            #pragma unroll
            for (int nn = 0; nn < 2; ++nn) {
                int n = g * 2 + nn;
                #pragma unroll
                for (int j = 0; j < 4; ++j) {
                    float p = __expf(sacc[n][j] - Mst[j]);
                    if ((wls[j] >> (n * 16)) & 1ull) p = 0.0f;
                    Ps[wave][hi * 4 + j][nn * 16 + lo] = f2bf(p);
                }
            }
            bf16x8 a2 = *(const bf16x8*)&Ps[wave][lo][hi * 8];
            #pragma unroll
            for (int n = 0; n < 16; ++n) {
                bf16x8 bv = *(const bf16x8*)&Vs[n * 16 + lo][g * 32 + hi * 8];
                oacc[n] = __builtin_amdgcn_mfma_f32_16x16x32_bf16(a2, bv, oacc[n], 0, 0, 0);
            }
            lacc = __builtin_amdgcn_mfma_f32_16x16x32_bf16(a2, onesf, lacc, 0, 0, 0);
        }
        #pragma unroll
        for (int j = 0; j < 4; ++j)
            Lst[j] += lacc[j];
    }

    // --- epilogue: bf16 raw partials ---
    const size_t obase = ((size_t)split * 16384 + qg0) * 256;
    #pragma unroll
    for (int n = 0; n < 16; ++n)
        #pragma unroll
        for (int j = 0; j < 4; ++j)
            Opart[obase + (size_t)(hi * 4 + j) * 256 + n * 16 + lo] = f2bf(oacc[n][j]);
    if (lo == 0) {
        #pragma unroll
        for (int j = 0; j < 4; ++j) {
            size_t r = (size_t)split * 16384 + qg0 + hi * 4 + j;
            Mpart[r] = Mst[j];
            Lpart[r] = Lst[j];
        }
    }
}

// ---------------------------------------------------------------------------
// Combine the two KV-split partials.  grid 4096, block 256, 4 floats/thread.
// ---------------------------------------------------------------------------
__global__ __launch_bounds__(256)
void combine_kernel(const short* __restrict__ Opart,
                    const float* __restrict__ Mpart,
                    const float* __restrict__ Lpart,
                    float* __restrict__ out)
{
    int gid = blockIdx.x * 256 + threadIdx.x;   // 1,048,576 threads
    int row = gid >> 6, c4 = gid & 63;
    float M0 = Mpart[row], M1 = Mpart[16384 + row];
    float L0 = Lpart[row], L1 = Lpart[16384 + row];
    float M = fmaxf(M0, M1);
    float w0 = __expf(M0 - M), w1 = __expf(M1 - M);
    float inv = 1.0f / (w0 * L0 + w1 * L1);
    short4 o0 = *(const short4*)(Opart + (size_t)row * 256 + c4 * 4);
    short4 o1 = *(const short4*)(Opart + (size_t)16384 * 256 + (size_t)row * 256 + c4 * 4);
    float4 r;
    r.x = (w0 * bf2f(o0.x) + w1 * bf2f(o1.x)) * inv;
    r.y = (w0 * bf2f(o0.y) + w1 * bf2f(o1.y)) * inv;
    r.z = (w0 * bf2f(o0.z) + w1 * bf2f(o1.z)) * inv;
    r.w = (w0 * bf2f(o0.w) + w1 * bf2f(o1.w)) * inv;
    *(float4*)(out + (size_t)row * 256 + c4 * 4) = r;
}

// ---------------------------------------------------------------------------
extern "C" void kernel_launch(void* const* d_in, const int* in_sizes, int n_in,
                              void* d_out, int out_size, void* d_ws, size_t ws_size,
                              hipStream_t stream)
{
    const float* encq = (const float*)d_in[0];
    const float* enck = (const float*)d_in[1];
    const float* encv = (const float*)d_in[2];
    const int*   mask = (const int*)d_in[3];
    const float* Wq   = (const float*)d_in[4];
    const float* Wk   = (const float*)d_in[5];
    const float* Wv   = (const float*)d_in[6];

    char* ws = (char*)d_ws;
    short* q_ws  = (short*)(ws);                  //  8 MB  [16384][256] bf16
    short* k_ws  = (short*)(ws + 8388608);        //  8 MB
    short* vt_ws = (short*)(ws + 16777216);       //  8 MB  [4][256][4096] bf16
    short* Opart = (short*)(ws + 25165824);       // 16 MB  [2][16384][256] bf16
    float* Mpart = (float*)(ws + 41943040);       // 128 KB [2][16384]
    float* Lpart = (float*)(ws + 42074112);       // 128 KB
    unsigned long long* packed = (unsigned long long*)(ws + 42205184);  // 8 MB
    float* out   = (float*)d_out;                 // total ~48.2 MB

    hipLaunchKernelGGL(proj_kernel, dim3(128, 3), dim3(256), 0, stream,
                       encq, enck, encv, Wq, Wk, Wv, q_ws, k_ws, vt_ws);
    hipLaunchKernelGGL(maskpack_kernel, dim3(4096), dim3(256), 0, stream,
                       mask, packed);
    hipLaunchKernelGGL(attn_kernel, dim3(32, 4, 2), dim3(512), 0, stream,
                       q_ws, k_ws, vt_ws, packed, Opart, Mpart, Lpart);
    hipLaunchKernelGGL(combine_kernel, dim3(4096), dim3(256), 0, stream,
                       Opart, Mpart, Lpart, out);
}

// Round 8
// 251.430 us; speedup vs baseline: 1.5855x; 1.2924x over previous
//
#include <hip/hip_runtime.h>
#include <hip/hip_bf16.h>
#include <stdint.h>

// Attention_5265629905090: B=4, S=4096, D=256, fp32 in/out, int mask (1 = masked -> -1e9)
// R8: (a) attn async-STAGE split (T14): prologue reg-load, ds_write after barrier, next
// loads issued before compute -> HBM/L2 latency hides under QK/softmax/PV. (b) proj
// restructured 8 waves x 16 rows, launch_bounds(512,2) (mirror of R7 attn fix; proj was
// ~60us vs 12us floor at 1 wave/SIMD). R7: attn 156us, LDS-throughput-bound, conflicts 17M.

typedef __attribute__((ext_vector_type(8))) short bf16x8;
typedef __attribute__((ext_vector_type(4))) float f32x4;

__device__ __forceinline__ short f2bf(float f) {
    union { float f; uint32_t u; } v; v.f = f;
    uint32_t r = v.u + 0x7FFFu + ((v.u >> 16) & 1u);   // RNE
    return (short)(r >> 16);
}
__device__ __forceinline__ float bf2f(short s) {
    union { uint32_t u; float f; } v; v.u = ((uint32_t)(uint16_t)s) << 16;
    return v.f;
}

// ---------------------------------------------------------------------------
// Projection GEMM: C[s][e] = sum_d X[s][d] * W[e][d]   (nn.Linear, y = x W^T)
// grid (128, 3), block 512 (8 waves x 16 rows).  proj: 0=Q (scaled 1/16), 1=K, 2=V^T
// ---------------------------------------------------------------------------
__global__ __launch_bounds__(512, 2)
void proj_kernel(const float* __restrict__ encq,
                 const float* __restrict__ enck,
                 const float* __restrict__ encv,
                 const float* __restrict__ Wq,
                 const float* __restrict__ Wk,
                 const float* __restrict__ Wv,
                 short* __restrict__ q_out,   // [16384][256]
                 short* __restrict__ k_out,   // [16384][256]
                 short* __restrict__ vt_out)  // [4][256][4096]
{
    __shared__ short As[128][72];
    __shared__ short Bs[256][72];

    const int tid = threadIdx.x;
    const int wave = tid >> 6, lane = tid & 63, lo = lane & 15, hi = lane >> 4;
    const int proj = blockIdx.y;
    const int row0 = blockIdx.x * 128;

    const float* X = (proj == 0) ? encq : (proj == 1) ? enck : encv;
    const float* W = (proj == 0) ? Wq   : (proj == 1) ? Wk   : Wv;

    f32x4 acc[16];
    #pragma unroll
    for (int n = 0; n < 16; ++n) {
        f32x4 z = {0.f, 0.f, 0.f, 0.f};
        acc[n] = z;
    }

    for (int ks = 0; ks < 4; ++ks) {
        const int k0 = ks * 64;
        __syncthreads();
        // stage A tile: 128 x 64 fp32 -> bf16 (2048 4-short units / 512 threads)
        #pragma unroll
        for (int i = 0; i < 4; ++i) {
            int u = tid + i * 512;
            int r = u >> 4, c4 = u & 15;
            float4 v = *(const float4*)(X + (size_t)(row0 + r) * 256 + k0 + c4 * 4);
            short* dst = &As[r][c4 * 4];
            dst[0] = f2bf(v.x); dst[1] = f2bf(v.y); dst[2] = f2bf(v.z); dst[3] = f2bf(v.w);
        }
        // stage W tile: 256 x 64 (4096 units / 512 threads)
        #pragma unroll
        for (int i = 0; i < 8; ++i) {
            int u = tid + i * 512;
            int r = u >> 4, c4 = u & 15;
            float4 v = *(const float4*)(W + (size_t)r * 256 + k0 + c4 * 4);
            short* dst = &Bs[r][c4 * 4];
            dst[0] = f2bf(v.x); dst[1] = f2bf(v.y); dst[2] = f2bf(v.z); dst[3] = f2bf(v.w);
        }
        __syncthreads();
        #pragma unroll
        for (int kl = 0; kl < 2; ++kl) {
            bf16x8 a = *(const bf16x8*)&As[wave * 16 + lo][kl * 32 + hi * 8];
            #pragma unroll
            for (int n = 0; n < 16; ++n) {
                bf16x8 b = *(const bf16x8*)&Bs[n * 16 + lo][kl * 32 + hi * 8];
                acc[n] = __builtin_amdgcn_mfma_f32_16x16x32_bf16(a, b, acc[n], 0, 0, 0);
            }
        }
    }

    // epilogue: C-frag row = (lane>>4)*4 + j, col = lane&15
    #pragma unroll
    for (int n = 0; n < 16; ++n)
        #pragma unroll
        for (int j = 0; j < 4; ++j) {
            int srow = row0 + wave * 16 + hi * 4 + j;
            int e = n * 16 + lo;
            float v = acc[n][j];
            if (proj == 0) {
                q_out[(size_t)srow * 256 + e] = f2bf(v * 0.0625f);
            } else if (proj == 1) {
                k_out[(size_t)srow * 256 + e] = f2bf(v);
            } else {
                int b = srow >> 12, s = srow & 4095;
                vt_out[((size_t)b * 256 + e) * 4096 + s] = f2bf(v);
            }
        }
}

// ---------------------------------------------------------------------------
// Mask bit-pack (ballot-free): one thread -> one u64 word (16 x int4 local pack).
// grid 4096, block 256.  [16384][4096] int32 -> [16384][64] u64.
// ---------------------------------------------------------------------------
__global__ __launch_bounds__(256)
void maskpack_kernel(const int* __restrict__ mask,
                     unsigned long long* __restrict__ packed)
{
    const int gid = blockIdx.x * 256 + threadIdx.x;   // 0 .. 1048575
    const int row = gid >> 6, w = gid & 63;
    const int4* src = (const int4*)(mask + (size_t)row * 4096 + w * 64);
    uint32_t lo32 = 0, hi32 = 0;
    #pragma unroll
    for (int it = 0; it < 8; ++it) {
        int4 v = src[it];
        lo32 |= (uint32_t)(v.x != 0) << (it * 4);
        lo32 |= (uint32_t)(v.y != 0) << (it * 4 + 1);
        lo32 |= (uint32_t)(v.z != 0) << (it * 4 + 2);
        lo32 |= (uint32_t)(v.w != 0) << (it * 4 + 3);
    }
    #pragma unroll
    for (int it = 0; it < 8; ++it) {
        int4 v = src[8 + it];
        hi32 |= (uint32_t)(v.x != 0) << (it * 4);
        hi32 |= (uint32_t)(v.y != 0) << (it * 4 + 1);
        hi32 |= (uint32_t)(v.z != 0) << (it * 4 + 2);
        hi32 |= (uint32_t)(v.w != 0) << (it * 4 + 3);
    }
    packed[(size_t)row * 64 + w] = (unsigned long long)lo32
                                 | ((unsigned long long)hi32 << 32);
}

// ---------------------------------------------------------------------------
// Flash attention, split-KV x2. grid (32, 4, 2), block 512 (8 waves x 16 q-rows).
// KVBLK = 64, 32 tiles/block. LDS 80896 B, 2 waves/SIMD. Async-stage (T14):
// reg prologue load; per iter {sync; ds_write; sync; issue t+1 loads; compute}.
// ---------------------------------------------------------------------------
__global__ __launch_bounds__(512, 2)
void attn_kernel(const short* __restrict__ qs,   // [16384][256] prescaled
                 const short* __restrict__ kk_,  // [16384][256]
                 const short* __restrict__ vt,   // [4][256][4096]
                 const unsigned long long* __restrict__ pk, // [16384][64]
                 short* __restrict__ Opart,      // [2][16384][256] bf16
                 float* __restrict__ Mpart,      // [2][16384]
                 float* __restrict__ Lpart)      // [2][16384]
{
    __shared__ short Ks[64][264];      // 33792 B
    __shared__ short Vs[256][72];      // 36864 B
    __shared__ short Ps[8][16][40];    // 10240 B   (total 80896)

    const int tid = threadIdx.x;
    const int wave = tid >> 6, lane = tid & 63, lo = lane & 15, hi = lane >> 4;
    const int qt = blockIdx.x, b = blockIdx.y, split = blockIdx.z;
    const int qrow0 = qt * 128 + wave * 16;           // q row base within batch
    const size_t qg0 = (size_t)b * 4096 + qrow0;      // global q row base
    const int kv0 = split * 2048;

    // resident Q fragments (16 rows): A-frag row = lane&15, k = (lane>>4)*8..+8
    bf16x8 qf[8];
    #pragma unroll
    for (int kk = 0; kk < 8; ++kk)
        qf[kk] = *(const bf16x8*)(qs + (qg0 + lo) * 256 + kk * 32 + hi * 8);

    f32x4 oacc[16];
    #pragma unroll
    for (int n = 0; n < 16; ++n) {
        f32x4 z = {0.f, 0.f, 0.f, 0.f};
        oacc[n] = z;
    }
    float Mst[4], Lst[4];
    #pragma unroll
    for (int j = 0; j < 4; ++j) { Mst[j] = -1e30f; Lst[j] = 0.f; }

    bf16x8 onesf;
    #pragma unroll
    for (int i = 0; i < 8; ++i) onesf[i] = (short)0x3F80;   // bf16 1.0

    const short* ksrc0 = kk_ + ((size_t)b * 4096 + kv0) * 256;
    const size_t vbase = (size_t)b * 256 * 4096;
    const unsigned long long* pkbase = pk + qg0 * 64 + split * 32;

    // --- prologue: issue t=0 staging loads into regs ---
    bf16x8 kreg[4], vreg[4];
    #pragma unroll
    for (int i = 0; i < 4; ++i) {
        int u = tid + i * 512;
        kreg[i] = *(const bf16x8*)(ksrc0 + u * 8);
    }
    #pragma unroll
    for (int i = 0; i < 4; ++i) {
        int u = tid + i * 512;
        int r = u >> 3, cu = u & 7;
        vreg[i] = *(const bf16x8*)(vt + vbase + (size_t)r * 4096 + kv0 + cu * 8);
    }

    for (int t = 0; t < 32; ++t) {
        __syncthreads();   // prior iteration done reading Ks/Vs
        // --- commit staged regs to LDS ---
        #pragma unroll
        for (int i = 0; i < 4; ++i) {
            int u = tid + i * 512;
            *(bf16x8*)&Ks[u >> 5][(u & 31) * 8] = kreg[i];
        }
        #pragma unroll
        for (int i = 0; i < 4; ++i) {
            int u = tid + i * 512;
            int r = u >> 3, cu = u & 7;
            *(bf16x8*)&Vs[r][cu * 8] = vreg[i];
        }
        __syncthreads();   // barrier drains this wave's ds_writes -> regs reusable

        // --- issue t+1 staging loads; in flight during compute below ---
        if (t < 31) {
            const short* src = ksrc0 + (size_t)(t + 1) * 64 * 256;
            #pragma unroll
            for (int i = 0; i < 4; ++i) {
                int u = tid + i * 512;
                kreg[i] = *(const bf16x8*)(src + u * 8);
            }
            const int c0 = kv0 + (t + 1) * 64;
            #pragma unroll
            for (int i = 0; i < 4; ++i) {
                int u = tid + i * 512;
                int r = u >> 3, cu = u & 7;
                vreg[i] = *(const bf16x8*)(vt + vbase + (size_t)r * 4096 + c0 + cu * 8);
            }
        }

        // --- mask bit-words: row hi*4+j, bit (n*16+lo) after >>lo ---
        unsigned long long wls[4];
        #pragma unroll
        for (int j = 0; j < 4; ++j)
            wls[j] = pkbase[(size_t)(hi * 4 + j) * 64 + t] >> lo;

        // --- QK^T: S[16q][64k] ---
        f32x4 sacc[4];
        #pragma unroll
        for (int n = 0; n < 4; ++n) {
            f32x4 z = {0.f, 0.f, 0.f, 0.f};
            sacc[n] = z;
        }
        #pragma unroll
        for (int kk = 0; kk < 8; ++kk) {
            #pragma unroll
            for (int n = 0; n < 4; ++n) {
                bf16x8 bk = *(const bf16x8*)&Ks[n * 16 + lo][kk * 32 + hi * 8];
                sacc[n] = __builtin_amdgcn_mfma_f32_16x16x32_bf16(qf[kk], bk, sacc[n], 0, 0, 0);
            }
        }

        // --- row max (masked), butterfly over the 16-lane column group ---
        float ml[4];
        #pragma unroll
        for (int j = 0; j < 4; ++j) {
            float mx = -1e30f;
            #pragma unroll
            for (int n = 0; n < 4; ++n) {
                float s = sacc[n][j];
                if ((wls[j] >> (n * 16)) & 1ull) s = -1e30f;
                mx = fmaxf(mx, s);
            }
            #pragma unroll
            for (int d = 1; d < 16; d <<= 1)
                mx = fmaxf(mx, __shfl_xor(mx, d));
            ml[j] = mx;
        }

        // --- defer-max rescale (THR = 8) ---
        bool needl = false;
        #pragma unroll
        for (int j = 0; j < 4; ++j)
            needl = needl || (ml[j] > Mst[j] + 8.0f);
        if (__any((int)needl)) {
            #pragma unroll
            for (int j = 0; j < 4; ++j) {
                float Mn = fmaxf(Mst[j], ml[j]);
                float sc = __expf(Mst[j] - Mn);
                Mst[j] = Mn;
                Lst[j] *= sc;
                #pragma unroll
                for (int n = 0; n < 16; ++n) oacc[n][j] *= sc;
            }
        }

        // --- PV in two k-halves through the per-wave P buffer ---
        f32x4 lacc = {0.f, 0.f, 0.f, 0.f};
        #pragma unroll
        for (int g = 0; g < 2; ++g) {
            #pragma unroll
            for (int nn = 0; nn < 2; ++nn) {
                int n = g * 2 + nn;
                #pragma unroll
                for (int j = 0; j < 4; ++j) {
                    float p = __expf(sacc[n][j] - Mst[j]);
                    if ((wls[j] >> (n * 16)) & 1ull) p = 0.0f;
                    Ps[wave][hi * 4 + j][nn * 16 + lo] = f2bf(p);
                }
            }
            bf16x8 a2 = *(const bf16x8*)&Ps[wave][lo][hi * 8];
            #pragma unroll
            for (int n = 0; n < 16; ++n) {
                bf16x8 bv = *(const bf16x8*)&Vs[n * 16 + lo][g * 32 + hi * 8];
                oacc[n] = __builtin_amdgcn_mfma_f32_16x16x32_bf16(a2, bv, oacc[n], 0, 0, 0);
            }
            lacc = __builtin_amdgcn_mfma_f32_16x16x32_bf16(a2, onesf, lacc, 0, 0, 0);
        }
        #pragma unroll
        for (int j = 0; j < 4; ++j)
            Lst[j] += lacc[j];
    }

    // --- epilogue: bf16 raw partials ---
    const size_t obase = ((size_t)split * 16384 + qg0) * 256;
    #pragma unroll
    for (int n = 0; n < 16; ++n)
        #pragma unroll
        for (int j = 0; j < 4; ++j)
            Opart[obase + (size_t)(hi * 4 + j) * 256 + n * 16 + lo] = f2bf(oacc[n][j]);
    if (lo == 0) {
        #pragma unroll
        for (int j = 0; j < 4; ++j) {
            size_t r = (size_t)split * 16384 + qg0 + hi * 4 + j;
            Mpart[r] = Mst[j];
            Lpart[r] = Lst[j];
        }
    }
}

// ---------------------------------------------------------------------------
// Combine the two KV-split partials.  grid 4096, block 256, 4 floats/thread.
// ---------------------------------------------------------------------------
__global__ __launch_bounds__(256)
void combine_kernel(const short* __restrict__ Opart,
                    const float* __restrict__ Mpart,
                    const float* __restrict__ Lpart,
                    float* __restrict__ out)
{
    int gid = blockIdx.x * 256 + threadIdx.x;   // 1,048,576 threads
    int row = gid >> 6, c4 = gid & 63;
    float M0 = Mpart[row], M1 = Mpart[16384 + row];
    float L0 = Lpart[row], L1 = Lpart[16384 + row];
    float M = fmaxf(M0, M1);
    float w0 = __expf(M0 - M), w1 = __expf(M1 - M);
    float inv = 1.0f / (w0 * L0 + w1 * L1);
    short4 o0 = *(const short4*)(Opart + (size_t)row * 256 + c4 * 4);
    short4 o1 = *(const short4*)(Opart + (size_t)16384 * 256 + (size_t)row * 256 + c4 * 4);
    float4 r;
    r.x = (w0 * bf2f(o0.x) + w1 * bf2f(o1.x)) * inv;
    r.y = (w0 * bf2f(o0.y) + w1 * bf2f(o1.y)) * inv;
    r.z = (w0 * bf2f(o0.z) + w1 * bf2f(o1.z)) * inv;
    r.w = (w0 * bf2f(o0.w) + w1 * bf2f(o1.w)) * inv;
    *(float4*)(out + (size_t)row * 256 + c4 * 4) = r;
}

// ---------------------------------------------------------------------------
extern "C" void kernel_launch(void* const* d_in, const int* in_sizes, int n_in,
                              void* d_out, int out_size, void* d_ws, size_t ws_size,
                              hipStream_t stream)
{
    const float* encq = (const float*)d_in[0];
    const float* enck = (const float*)d_in[1];
    const float* encv = (const float*)d_in[2];
    const int*   mask = (const int*)d_in[3];
    const float* Wq   = (const float*)d_in[4];
    const float* Wk   = (const float*)d_in[5];
    const float* Wv   = (const float*)d_in[6];

    char* ws = (char*)d_ws;
    short* q_ws  = (short*)(ws);                  //  8 MB  [16384][256] bf16
    short* k_ws  = (short*)(ws + 8388608);        //  8 MB
    short* vt_ws = (short*)(ws + 16777216);       //  8 MB  [4][256][4096] bf16
    short* Opart = (short*)(ws + 25165824);       // 16 MB  [2][16384][256] bf16
    float* Mpart = (float*)(ws + 41943040);       // 128 KB [2][16384]
    float* Lpart = (float*)(ws + 42074112);       // 128 KB
    unsigned long long* packed = (unsigned long long*)(ws + 42205184);  // 8 MB
    float* out   = (float*)d_out;                 // total ~48.2 MB

    hipLaunchKernelGGL(proj_kernel, dim3(128, 3), dim3(512), 0, stream,
                       encq, enck, encv, Wq, Wk, Wv, q_ws, k_ws, vt_ws);
    hipLaunchKernelGGL(maskpack_kernel, dim3(4096), dim3(256), 0, stream,
                       mask, packed);
    hipLaunchKernelGGL(attn_kernel, dim3(32, 4, 2), dim3(512), 0, stream,
                       q_ws, k_ws, vt_ws, packed, Opart, Mpart, Lpart);
    hipLaunchKernelGGL(combine_kernel, dim3(4096), dim3(256), 0, stream,
                       Opart, Mpart, Lpart, out);
}

// Round 9
// 194.679 us; speedup vs baseline: 2.0477x; 1.2915x over previous
//
#include <hip/hip_runtime.h>
#include <hip/hip_bf16.h>
#include <stdint.h>

// Attention_5265629905090: B=4, S=4096, D=256, fp32 in/out, int mask (1 = masked -> -1e9)
// R9: FUSE mask bit-pack into attn staging (kills the ~52us maskpack kernel). Per iter,
// 512 threads each load one (row,16col) run of the mask tile (4x int4, 64B contiguous),
// pack 16 bits, write u16 -> 1KB LDS bitmap; lanes read row-words as broadcast b64.
// Mask loads ride the R8 T14 async pipeline (issue with K/V, commit after barrier).
// LDS 81920 (=80KB, still 2 blocks/CU). R8: total 251us (attn ~125, maskpack ~52).

typedef __attribute__((ext_vector_type(8))) short bf16x8;
typedef __attribute__((ext_vector_type(4))) float f32x4;

__device__ __forceinline__ short f2bf(float f) {
    union { float f; uint32_t u; } v; v.f = f;
    uint32_t r = v.u + 0x7FFFu + ((v.u >> 16) & 1u);   // RNE
    return (short)(r >> 16);
}
__device__ __forceinline__ float bf2f(short s) {
    union { uint32_t u; float f; } v; v.u = ((uint32_t)(uint16_t)s) << 16;
    return v.f;
}

// ---------------------------------------------------------------------------
// Projection GEMM: C[s][e] = sum_d X[s][d] * W[e][d]   (nn.Linear, y = x W^T)
// grid (128, 3), block 512 (8 waves x 16 rows).  proj: 0=Q (scaled 1/16), 1=K, 2=V^T
// ---------------------------------------------------------------------------
__global__ __launch_bounds__(512, 2)
void proj_kernel(const float* __restrict__ encq,
                 const float* __restrict__ enck,
                 const float* __restrict__ encv,
                 const float* __restrict__ Wq,
                 const float* __restrict__ Wk,
                 const float* __restrict__ Wv,
                 short* __restrict__ q_out,   // [16384][256]
                 short* __restrict__ k_out,   // [16384][256]
                 short* __restrict__ vt_out)  // [4][256][4096]
{
    __shared__ short As[128][72];
    __shared__ short Bs[256][72];

    const int tid = threadIdx.x;
    const int wave = tid >> 6, lane = tid & 63, lo = lane & 15, hi = lane >> 4;
    const int proj = blockIdx.y;
    const int row0 = blockIdx.x * 128;

    const float* X = (proj == 0) ? encq : (proj == 1) ? enck : encv;
    const float* W = (proj == 0) ? Wq   : (proj == 1) ? Wk   : Wv;

    f32x4 acc[16];
    #pragma unroll
    for (int n = 0; n < 16; ++n) {
        f32x4 z = {0.f, 0.f, 0.f, 0.f};
        acc[n] = z;
    }

    for (int ks = 0; ks < 4; ++ks) {
        const int k0 = ks * 64;
        __syncthreads();
        #pragma unroll
        for (int i = 0; i < 4; ++i) {
            int u = tid + i * 512;
            int r = u >> 4, c4 = u & 15;
            float4 v = *(const float4*)(X + (size_t)(row0 + r) * 256 + k0 + c4 * 4);
            short* dst = &As[r][c4 * 4];
            dst[0] = f2bf(v.x); dst[1] = f2bf(v.y); dst[2] = f2bf(v.z); dst[3] = f2bf(v.w);
        }
        #pragma unroll
        for (int i = 0; i < 8; ++i) {
            int u = tid + i * 512;
            int r = u >> 4, c4 = u & 15;
            float4 v = *(const float4*)(W + (size_t)r * 256 + k0 + c4 * 4);
            short* dst = &Bs[r][c4 * 4];
            dst[0] = f2bf(v.x); dst[1] = f2bf(v.y); dst[2] = f2bf(v.z); dst[3] = f2bf(v.w);
        }
        __syncthreads();
        #pragma unroll
        for (int kl = 0; kl < 2; ++kl) {
            bf16x8 a = *(const bf16x8*)&As[wave * 16 + lo][kl * 32 + hi * 8];
            #pragma unroll
            for (int n = 0; n < 16; ++n) {
                bf16x8 b = *(const bf16x8*)&Bs[n * 16 + lo][kl * 32 + hi * 8];
                acc[n] = __builtin_amdgcn_mfma_f32_16x16x32_bf16(a, b, acc[n], 0, 0, 0);
            }
        }
    }

    #pragma unroll
    for (int n = 0; n < 16; ++n)
        #pragma unroll
        for (int j = 0; j < 4; ++j) {
            int srow = row0 + wave * 16 + hi * 4 + j;
            int e = n * 16 + lo;
            float v = acc[n][j];
            if (proj == 0) {
                q_out[(size_t)srow * 256 + e] = f2bf(v * 0.0625f);
            } else if (proj == 1) {
                k_out[(size_t)srow * 256 + e] = f2bf(v);
            } else {
                int b = srow >> 12, s = srow & 4095;
                vt_out[((size_t)b * 256 + e) * 4096 + s] = f2bf(v);
            }
        }
}

// ---------------------------------------------------------------------------
// Flash attention, split-KV x2. grid (32, 4, 2), block 512 (8 waves x 16 q-rows).
// KVBLK = 64, 32 tiles/block. LDS 81920 B. Async-stage (T14) for K, V^T, AND the
// raw mask tile (fused bit-pack -> 1KB LDS bitmap, one u64 row-word per q-row).
// ---------------------------------------------------------------------------
__global__ __launch_bounds__(512, 2)
void attn_kernel(const short* __restrict__ qs,   // [16384][256] prescaled
                 const short* __restrict__ kk_,  // [16384][256]
                 const short* __restrict__ vt,   // [4][256][4096]
                 const int*   __restrict__ mask, // [4][4096][4096]
                 short* __restrict__ Opart,      // [2][16384][256] bf16
                 float* __restrict__ Mpart,      // [2][16384]
                 float* __restrict__ Lpart)      // [2][16384]
{
    __shared__ short Ks[64][264];               // 33792 B
    __shared__ short Vs[256][72];               // 36864 B
    __shared__ short Ps[8][16][40];             // 10240 B
    __shared__ unsigned long long Mb[128];      //  1024 B   (total 81920)

    const int tid = threadIdx.x;
    const int wave = tid >> 6, lane = tid & 63, lo = lane & 15, hi = lane >> 4;
    const int qt = blockIdx.x, b = blockIdx.y, split = blockIdx.z;
    const int qrow0 = qt * 128 + wave * 16;           // q row base within batch
    const size_t qg0 = (size_t)b * 4096 + qrow0;      // global q row base
    const int kv0 = split * 2048;

    // resident Q fragments (16 rows): A-frag row = lane&15, k = (lane>>4)*8..+8
    bf16x8 qf[8];
    #pragma unroll
    for (int kk = 0; kk < 8; ++kk)
        qf[kk] = *(const bf16x8*)(qs + (qg0 + lo) * 256 + kk * 32 + hi * 8);

    f32x4 oacc[16];
    #pragma unroll
    for (int n = 0; n < 16; ++n) {
        f32x4 z = {0.f, 0.f, 0.f, 0.f};
        oacc[n] = z;
    }
    float Mst[4], Lst[4];
    #pragma unroll
    for (int j = 0; j < 4; ++j) { Mst[j] = -1e30f; Lst[j] = 0.f; }

    bf16x8 onesf;
    #pragma unroll
    for (int i = 0; i < 8; ++i) onesf[i] = (short)0x3F80;   // bf16 1.0

    const short* ksrc0 = kk_ + ((size_t)b * 4096 + kv0) * 256;
    const size_t vbase = (size_t)b * 256 * 4096;
    // mask staging: thread owns (row = tid>>2, part = tid&3): 16 consecutive ints
    const int mrow = tid >> 2, mpart = tid & 3;
    const int* msrc0 = mask + (size_t)b * 4096 * 4096
                     + (size_t)(qt * 128 + mrow) * 4096 + kv0 + mpart * 16;

    // --- prologue: issue t=0 staging loads into regs ---
    bf16x8 kreg[4], vreg[4];
    int4 mreg[4];
    #pragma unroll
    for (int i = 0; i < 4; ++i) {
        int u = tid + i * 512;
        kreg[i] = *(const bf16x8*)(ksrc0 + u * 8);
    }
    #pragma unroll
    for (int i = 0; i < 4; ++i) {
        int u = tid + i * 512;
        int r = u >> 3, cu = u & 7;
        vreg[i] = *(const bf16x8*)(vt + vbase + (size_t)r * 4096 + kv0 + cu * 8);
    }
    #pragma unroll
    for (int i = 0; i < 4; ++i)
        mreg[i] = *(const int4*)(msrc0 + i * 4);

    for (int t = 0; t < 32; ++t) {
        __syncthreads();   // prior iteration done reading Ks/Vs/Mb
        // --- commit staged regs to LDS ---
        #pragma unroll
        for (int i = 0; i < 4; ++i) {
            int u = tid + i * 512;
            *(bf16x8*)&Ks[u >> 5][(u & 31) * 8] = kreg[i];
        }
        #pragma unroll
        for (int i = 0; i < 4; ++i) {
            int u = tid + i * 512;
            int r = u >> 3, cu = u & 7;
            *(bf16x8*)&Vs[r][cu * 8] = vreg[i];
        }
        {
            uint32_t mb = 0;
            #pragma unroll
            for (int i = 0; i < 4; ++i) {
                mb |= (uint32_t)(mreg[i].x != 0) << (i * 4);
                mb |= (uint32_t)(mreg[i].y != 0) << (i * 4 + 1);
                mb |= (uint32_t)(mreg[i].z != 0) << (i * 4 + 2);
                mb |= (uint32_t)(mreg[i].w != 0) << (i * 4 + 3);
            }
            ((unsigned short*)&Mb[mrow])[mpart] = (unsigned short)mb;
        }
        __syncthreads();   // LDS tile + bitmap ready; staged regs reusable

        // --- issue t+1 staging loads; in flight during compute below ---
        if (t < 31) {
            const short* src = ksrc0 + (size_t)(t + 1) * 64 * 256;
            #pragma unroll
            for (int i = 0; i < 4; ++i) {
                int u = tid + i * 512;
                kreg[i] = *(const bf16x8*)(src + u * 8);
            }
            const int c0 = kv0 + (t + 1) * 64;
            #pragma unroll
            for (int i = 0; i < 4; ++i) {
                int u = tid + i * 512;
                int r = u >> 3, cu = u & 7;
                vreg[i] = *(const bf16x8*)(vt + vbase + (size_t)r * 4096 + c0 + cu * 8);
            }
            const int* ms = msrc0 + (t + 1) * 64;
            #pragma unroll
            for (int i = 0; i < 4; ++i)
                mreg[i] = *(const int4*)(ms + i * 4);
        }

        // --- mask bit-words from LDS bitmap: row wave*16+hi*4+j, bits >> lo ---
        unsigned long long wls[4];
        #pragma unroll
        for (int j = 0; j < 4; ++j)
            wls[j] = Mb[wave * 16 + hi * 4 + j] >> lo;

        // --- QK^T: S[16q][64k] ---
        f32x4 sacc[4];
        #pragma unroll
        for (int n = 0; n < 4; ++n) {
            f32x4 z = {0.f, 0.f, 0.f, 0.f};
            sacc[n] = z;
        }
        #pragma unroll
        for (int kk = 0; kk < 8; ++kk) {
            #pragma unroll
            for (int n = 0; n < 4; ++n) {
                bf16x8 bk = *(const bf16x8*)&Ks[n * 16 + lo][kk * 32 + hi * 8];
                sacc[n] = __builtin_amdgcn_mfma_f32_16x16x32_bf16(qf[kk], bk, sacc[n], 0, 0, 0);
            }
        }

        // --- row max (masked), butterfly over the 16-lane column group ---
        float ml[4];
        #pragma unroll
        for (int j = 0; j < 4; ++j) {
            float mx = -1e30f;
            #pragma unroll
            for (int n = 0; n < 4; ++n) {
                float s = sacc[n][j];
                if ((wls[j] >> (n * 16)) & 1ull) s = -1e30f;
                mx = fmaxf(mx, s);
            }
            #pragma unroll
            for (int d = 1; d < 16; d <<= 1)
                mx = fmaxf(mx, __shfl_xor(mx, d));
            ml[j] = mx;
        }

        // --- defer-max rescale (THR = 8) ---
        bool needl = false;
        #pragma unroll
        for (int j = 0; j < 4; ++j)
            needl = needl || (ml[j] > Mst[j] + 8.0f);
        if (__any((int)needl)) {
            #pragma unroll
            for (int j = 0; j < 4; ++j) {
                float Mn = fmaxf(Mst[j], ml[j]);
                float sc = __expf(Mst[j] - Mn);
                Mst[j] = Mn;
                Lst[j] *= sc;
                #pragma unroll
                for (int n = 0; n < 16; ++n) oacc[n][j] *= sc;
            }
        }

        // --- PV in two k-halves through the per-wave P buffer ---
        f32x4 lacc = {0.f, 0.f, 0.f, 0.f};
        #pragma unroll
        for (int g = 0; g < 2; ++g) {
            #pragma unroll
            for (int nn = 0; nn < 2; ++nn) {
                int n = g * 2 + nn;
                #pragma unroll
                for (int j = 0; j < 4; ++j) {
                    float p = __expf(sacc[n][j] - Mst[j]);
                    if ((wls[j] >> (n * 16)) & 1ull) p = 0.0f;
                    Ps[wave][hi * 4 + j][nn * 16 + lo] = f2bf(p);
                }
            }
            bf16x8 a2 = *(const bf16x8*)&Ps[wave][lo][hi * 8];
            #pragma unroll
            for (int n = 0; n < 16; ++n) {
                bf16x8 bv = *(const bf16x8*)&Vs[n * 16 + lo][g * 32 + hi * 8];
                oacc[n] = __builtin_amdgcn_mfma_f32_16x16x32_bf16(a2, bv, oacc[n], 0, 0, 0);
            }
            lacc = __builtin_amdgcn_mfma_f32_16x16x32_bf16(a2, onesf, lacc, 0, 0, 0);
        }
        #pragma unroll
        for (int j = 0; j < 4; ++j)
            Lst[j] += lacc[j];
    }

    // --- epilogue: bf16 raw partials ---
    const size_t obase = ((size_t)split * 16384 + qg0) * 256;
    #pragma unroll
    for (int n = 0; n < 16; ++n)
        #pragma unroll
        for (int j = 0; j < 4; ++j)
            Opart[obase + (size_t)(hi * 4 + j) * 256 + n * 16 + lo] = f2bf(oacc[n][j]);
    if (lo == 0) {
        #pragma unroll
        for (int j = 0; j < 4; ++j) {
            size_t r = (size_t)split * 16384 + qg0 + hi * 4 + j;
            Mpart[r] = Mst[j];
            Lpart[r] = Lst[j];
        }
    }
}

// ---------------------------------------------------------------------------
// Combine the two KV-split partials.  grid 4096, block 256, 4 floats/thread.
// ---------------------------------------------------------------------------
__global__ __launch_bounds__(256)
void combine_kernel(const short* __restrict__ Opart,
                    const float* __restrict__ Mpart,
                    const float* __restrict__ Lpart,
                    float* __restrict__ out)
{
    int gid = blockIdx.x * 256 + threadIdx.x;   // 1,048,576 threads
    int row = gid >> 6, c4 = gid & 63;
    float M0 = Mpart[row], M1 = Mpart[16384 + row];
    float L0 = Lpart[row], L1 = Lpart[16384 + row];
    float M = fmaxf(M0, M1);
    float w0 = __expf(M0 - M), w1 = __expf(M1 - M);
    float inv = 1.0f / (w0 * L0 + w1 * L1);
    short4 o0 = *(const short4*)(Opart + (size_t)row * 256 + c4 * 4);
    short4 o1 = *(const short4*)(Opart + (size_t)16384 * 256 + (size_t)row * 256 + c4 * 4);
    float4 r;
    r.x = (w0 * bf2f(o0.x) + w1 * bf2f(o1.x)) * inv;
    r.y = (w0 * bf2f(o0.y) + w1 * bf2f(o1.y)) * inv;
    r.z = (w0 * bf2f(o0.z) + w1 * bf2f(o1.z)) * inv;
    r.w = (w0 * bf2f(o0.w) + w1 * bf2f(o1.w)) * inv;
    *(float4*)(out + (size_t)row * 256 + c4 * 4) = r;
}

// ---------------------------------------------------------------------------
extern "C" void kernel_launch(void* const* d_in, const int* in_sizes, int n_in,
                              void* d_out, int out_size, void* d_ws, size_t ws_size,
                              hipStream_t stream)
{
    const float* encq = (const float*)d_in[0];
    const float* enck = (const float*)d_in[1];
    const float* encv = (const float*)d_in[2];
    const int*   mask = (const int*)d_in[3];
    const float* Wq   = (const float*)d_in[4];
    const float* Wk   = (const float*)d_in[5];
    const float* Wv   = (const float*)d_in[6];

    char* ws = (char*)d_ws;
    short* q_ws  = (short*)(ws);                  //  8 MB  [16384][256] bf16
    short* k_ws  = (short*)(ws + 8388608);        //  8 MB
    short* vt_ws = (short*)(ws + 16777216);       //  8 MB  [4][256][4096] bf16
    short* Opart = (short*)(ws + 25165824);       // 16 MB  [2][16384][256] bf16
    float* Mpart = (float*)(ws + 41943040);       // 128 KB [2][16384]
    float* Lpart = (float*)(ws + 42074112);       // 128 KB  (total ~40.5 MB)
    float* out   = (float*)d_out;

    hipLaunchKernelGGL(proj_kernel, dim3(128, 3), dim3(512), 0, stream,
                       encq, enck, encv, Wq, Wk, Wv, q_ws, k_ws, vt_ws);
    hipLaunchKernelGGL(attn_kernel, dim3(32, 4, 2), dim3(512), 0, stream,
                       q_ws, k_ws, vt_ws, mask, Opart, Mpart, Lpart);
    hipLaunchKernelGGL(combine_kernel, dim3(4096), dim3(256), 0, stream,
                       Opart, Mpart, Lpart, out);
}